// Round 13
// baseline (391.934 us; speedup 1.0000x reference)
//
#include <hip/hip_runtime.h>
#include <hip/hip_bf16.h>

// Problem constants: N=50000, E=800000, G=512, L=3, D=128
#define D_FEAT 128
#define N_GRAPHS 512
#define N_LAYERS 3
#define POOL_DIM (N_LAYERS * D_FEAT)   // 384
#define N_CLASSES 10
#define BN_EPS 1e-5f
#define CAP 64                         // fixed bucket capacity; P(deg>64) ~ 2e-18
#define NBINS 8
#define SLABCAP 768                    // per (bin,block) slab; mean 390, 13.5 sigma

// LESSON (r7): gather is latency-bound -> max occupancy + tiny footprint;
// GEMM tolerates low occupancy (MFMA-dense). Keep them separate kernels.
// LESSON (r3/r8): scatter regions written at <64B granularity by blocks on
// multiple XCDs get ~16x writeback amplification. Private slabs / XCD
// partitioning fix it.
// LESSON (r10): agg in-flight rows/SIMD is pinned by the VGPR occupancy
// cliff -> agg is at its LLC-gather floor (~7 TB/s effective); stop tuning.
// LESSON (r11): never shrink a small kernel's grid below ~256 blocks to buy
// data reuse — 64-block head ran at 2.5% occupancy, 70us. Latency-hiding,
// not traffic, is binding for sub-10us kernels.
// LESSON (r12->r13): 64-row GEMM tile = only 64 MFMAs between 4 barriers —
// barrier-bound. 128-row tile doubles MFMA per barrier.

typedef __attribute__((ext_vector_type(8))) short bf16x8;
typedef __attribute__((ext_vector_type(8))) unsigned short ushort8;
typedef __attribute__((ext_vector_type(4))) float f32x4;

__device__ __forceinline__ unsigned short f2bf(float f) {
    unsigned u = __builtin_bit_cast(unsigned, f);
    u += 0x7FFFu + ((u >> 16) & 1u);          // round-to-nearest-even
    return (unsigned short)(u >> 16);
}
__device__ __forceinline__ float bf2f(unsigned short h) {
    unsigned u = ((unsigned)h) << 16;
    return __builtin_bit_cast(float, u);
}
__device__ __forceinline__ float bf_lo(unsigned u) {
    return __builtin_bit_cast(float, u << 16);
}
__device__ __forceinline__ float bf_hi(unsigned u) {
    return __builtin_bit_cast(float, u & 0xffff0000u);
}

// ---------------------------------------------------------------------------
// Merged setup: cvt_x | cvt_w(LDS-transpose tiles) | prep | zero cursor |
// zero pooled | BIN (radix partition into per-(bin,block) private slabs).
// ---------------------------------------------------------------------------
__global__ __launch_bounds__(256) void setup_kernel(
        const float* __restrict__ x, unsigned short* __restrict__ xb,
        const float* __restrict__ W1, const float* __restrict__ W2,
        unsigned short* __restrict__ Wt,
        const float* __restrict__ b1, const float* __restrict__ gamma,
        const float* __restrict__ beta, const float* __restrict__ rm,
        const float* __restrict__ rv, const float* __restrict__ b2,
        float* __restrict__ ea, float* __restrict__ eb,
        int* __restrict__ cursor, float* __restrict__ pooled,
        const int* __restrict__ ei, int2* __restrict__ pairs,
        int* __restrict__ cnts, int E,
        int N, int n4, int B0, int B1, int B2, int B3, int B4) {
    int b = blockIdx.x, tid = threadIdx.x;
    if (b < B0) {                                     // cvt_x: fp32 -> bf16
        int i = b * 256 + tid;
        if (i < n4) {
            float4 v = ((const float4*)x)[i];
            ushort4 o;
            o.x = f2bf(v.x); o.y = f2bf(v.y); o.z = f2bf(v.z); o.w = f2bf(v.w);
            ((ushort4*)xb)[i] = o;
        }
    } else if (b < B1) {                              // cvt_w: coalesced transpose
        __shared__ float tile[64][65];
        int t = b - B0;                               // 0..23
        int slot = t >> 2;                            // 6 slots
        int r0 = ((t >> 1) & 1) * 64;                 // k-block in W rows
        int c0 = (t & 1) * 64;                        // n-block in W cols
        int l = slot >> 1;
        const float* W = (slot & 1) ? W2 : W1;
        const float* Wb = W + (size_t)l * D_FEAT * D_FEAT;
        int rr = tid >> 2, cc4 = (tid & 3) * 16;
        #pragma unroll
        for (int j = 0; j < 16; ++j)
            tile[rr][cc4 + j] = Wb[(size_t)(r0 + rr) * D_FEAT + c0 + cc4 + j];
        __syncthreads();
        int nn = tid >> 2, kk4 = (tid & 3) * 16;
        unsigned short* Wo = Wt + (size_t)slot * D_FEAT * D_FEAT;
        #pragma unroll
        for (int j = 0; j < 16; ++j)
            Wo[(size_t)(c0 + nn) * D_FEAT + r0 + kk4 + j] = f2bf(tile[kk4 + j][nn]);
    } else if (b < B2) {                              // prep: fold BN+bias
        int i = (b - B1) * 256 + tid;
        if (i < N_LAYERS * D_FEAT) {
            int l = i >> 7, c = i & 127;
            float s = gamma[i] * rsqrtf(rv[i] + BN_EPS);
            ea[(2 * l) * D_FEAT + c] = s;
            eb[(2 * l) * D_FEAT + c] = (b1[i] - rm[i]) * s + beta[i];
            ea[(2 * l + 1) * D_FEAT + c] = 1.0f;
            eb[(2 * l + 1) * D_FEAT + c] = b2[i];
        }
    } else if (b < B3) {                              // zero cursor
        int i = (b - B2) * 256 + tid;
        if (i < N) cursor[i] = 0;
    } else if (b < B4) {                              // zero pooled
        int i = (b - B3) * 256 + tid;
        if (i < N_GRAPHS * POOL_DIM) pooled[i] = 0.f;
    } else {                                          // bin: radix partition
        __shared__ int loc[NBINS];
        int bb = b - B4;                              // 0..255
        int per = (E + 255) / 256;
        int e0 = bb * per;
        int e1 = e0 + per; if (e1 > E) e1 = E;
        int span = (N + NBINS - 1) / NBINS;
        if (tid < NBINS) loc[tid] = 0;
        __syncthreads();
        for (int e = e0 + tid; e < e1; e += 256) {
            int dst = ei[E + e];
            int src = ei[e];
            int bin = dst / span;
            int p = atomicAdd(&loc[bin], 1);
            if (p < SLABCAP)
                pairs[((size_t)(bin * 256 + bb)) * SLABCAP + p] = make_int2(src, dst);
        }
        __syncthreads();
        if (tid < NBINS)
            cnts[tid * 256 + bb] = loc[tid];
    }
}

// ---------------------------------------------------------------------------
// Fill: blockIdx%8 = dst-range = XCD (CP round-robin): cursor atomics +
// bucket scatter stay in one XCD's L2. Dense slab reads.
// ---------------------------------------------------------------------------
__global__ __launch_bounds__(256) void fill_v3(const int2* __restrict__ pairs,
                                               const int* __restrict__ cnts,
                                               int* __restrict__ cursor,
                                               int* __restrict__ bucket) {
    int r = blockIdx.x & 7;
    int chunk = blockIdx.x >> 3;              // 0..63
    #pragma unroll
    for (int s = 0; s < 4; ++s) {
        int blk = chunk * 4 + s;              // 0..255
        int cnt = cnts[r * 256 + blk];
        if (cnt > SLABCAP) cnt = SLABCAP;
        const int2* slab = pairs + (size_t)(r * 256 + blk) * SLABCAP;
        for (int p = threadIdx.x; p < cnt; p += 256) {
            int2 pr = slab[p];
            int pos = atomicAdd(&cursor[pr.y], 1);
            if (pos < CAP) bucket[(size_t)pr.y * CAP + pos] = pr.x;
        }
    }
}

// ---------------------------------------------------------------------------
// Aggregation: one wave per TWO nodes, zero LDS, software-pipelined chunks;
// self-row loads hoisted ahead of the loop. (At the LLC-gather floor — r10.)
// ---------------------------------------------------------------------------
__global__ __launch_bounds__(256) void agg_kernel(const unsigned short* __restrict__ hprev,
                                                  const int* __restrict__ deg,
                                                  const int* __restrict__ bucket,
                                                  unsigned short* __restrict__ y, int n) {
    int wave = threadIdx.x >> 6, lane = threadIdx.x & 63;
    int n0 = (blockIdx.x * 4 + wave) * 2;
    if (n0 >= n) return;
    int n1 = n0 + 1;
    bool v1 = (n1 < n);
    int d0 = deg[n0]; if (d0 > CAP) d0 = CAP;
    int d1 = v1 ? deg[n1] : 0; if (d1 > CAP) d1 = CAP;
    int grp = lane >> 4, sub = lane & 15;
    const uint4* hp = (const uint4*)hprev;

    int idx0 = bucket[(size_t)n0 * CAP + lane];
    int idx1 = v1 ? bucket[(size_t)n1 * CAP + lane] : 0;

    uint4 s0v = hp[(size_t)n0 * 16 + sub];
    uint4 s1v = v1 ? hp[(size_t)n1 * 16 + sub] : make_uint4(0u, 0u, 0u, 0u);

    float a0[8] = {0.f,0.f,0.f,0.f,0.f,0.f,0.f,0.f};
    float a1[8] = {0.f,0.f,0.f,0.f,0.f,0.f,0.f,0.f};
    int dmax = d0 > d1 ? d0 : d1;

    auto issue = [&](int t, bool (&p0)[4], bool (&p1)[4],
                     uint4 (&w0)[4], uint4 (&w1)[4]) {
        #pragma unroll
        for (int q = 0; q < 4; ++q) {
            int e = t + q * 4 + grp;
            int s0 = __shfl(idx0, e & 63);
            int s1 = __shfl(idx1, e & 63);
            p0[q] = e < d0;
            p1[q] = e < d1;
            int r0 = p0[q] ? s0 : n0;
            int r1 = p1[q] ? s1 : n0;
            w0[q] = hp[(size_t)r0 * 16 + sub];
            w1[q] = hp[(size_t)r1 * 16 + sub];
        }
    };
    auto accum = [&](bool (&p0)[4], bool (&p1)[4],
                     uint4 (&w0)[4], uint4 (&w1)[4]) {
        #pragma unroll
        for (int q = 0; q < 4; ++q) {
            if (p0[q]) {
                uint4 v = w0[q];
                a0[0] += bf_lo(v.x); a0[1] += bf_hi(v.x);
                a0[2] += bf_lo(v.y); a0[3] += bf_hi(v.y);
                a0[4] += bf_lo(v.z); a0[5] += bf_hi(v.z);
                a0[6] += bf_lo(v.w); a0[7] += bf_hi(v.w);
            }
            if (p1[q]) {
                uint4 v = w1[q];
                a1[0] += bf_lo(v.x); a1[1] += bf_hi(v.x);
                a1[2] += bf_lo(v.y); a1[3] += bf_hi(v.y);
                a1[4] += bf_lo(v.z); a1[5] += bf_hi(v.z);
                a1[6] += bf_lo(v.w); a1[7] += bf_hi(v.w);
            }
        }
    };

    if (dmax > 0) {
        bool cp0[4], cp1[4];
        uint4 cw0[4], cw1[4];
        issue(0, cp0, cp1, cw0, cw1);
        for (int t = 16; t < dmax; t += 16) {
            bool np0[4], np1[4];
            uint4 nw0[4], nw1[4];
            issue(t, np0, np1, nw0, nw1);
            accum(cp0, cp1, cw0, cw1);
            #pragma unroll
            for (int q = 0; q < 4; ++q) {
                cp0[q] = np0[q]; cp1[q] = np1[q];
                cw0[q] = nw0[q]; cw1[q] = nw1[q];
            }
        }
        accum(cp0, cp1, cw0, cw1);
    }

    #pragma unroll
    for (int j = 0; j < 8; ++j) {
        a0[j] += __shfl_xor(a0[j], 16);
        a0[j] += __shfl_xor(a0[j], 32);
        a1[j] += __shfl_xor(a1[j], 16);
        a1[j] += __shfl_xor(a1[j], 32);
    }

    a0[0] += bf_lo(s0v.x); a0[1] += bf_hi(s0v.x);
    a0[2] += bf_lo(s0v.y); a0[3] += bf_hi(s0v.y);
    a0[4] += bf_lo(s0v.z); a0[5] += bf_hi(s0v.z);
    a0[6] += bf_lo(s0v.w); a0[7] += bf_hi(s0v.w);
    if (v1) {
        a1[0] += bf_lo(s1v.x); a1[1] += bf_hi(s1v.x);
        a1[2] += bf_lo(s1v.y); a1[3] += bf_hi(s1v.y);
        a1[4] += bf_lo(s1v.z); a1[5] += bf_hi(s1v.z);
        a1[6] += bf_lo(s1v.w); a1[7] += bf_hi(s1v.w);
    }

    if (grp == 0) {
        uint4 o;
        o.x = (unsigned)f2bf(a0[0]) | ((unsigned)f2bf(a0[1]) << 16);
        o.y = (unsigned)f2bf(a0[2]) | ((unsigned)f2bf(a0[3]) << 16);
        o.z = (unsigned)f2bf(a0[4]) | ((unsigned)f2bf(a0[5]) << 16);
        o.w = (unsigned)f2bf(a0[6]) | ((unsigned)f2bf(a0[7]) << 16);
        ((uint4*)y)[(size_t)n0 * 16 + sub] = o;
        if (v1) {
            uint4 p;
            p.x = (unsigned)f2bf(a1[0]) | ((unsigned)f2bf(a1[1]) << 16);
            p.y = (unsigned)f2bf(a1[2]) | ((unsigned)f2bf(a1[3]) << 16);
            p.z = (unsigned)f2bf(a1[4]) | ((unsigned)f2bf(a1[5]) << 16);
            p.w = (unsigned)f2bf(a1[6]) | ((unsigned)f2bf(a1[7]) << 16);
            ((uint4*)y)[(size_t)n1 * 16 + sub] = p;
        }
    }
}

// ---------------------------------------------------------------------------
// Fused layer GEMM, 128-row tile: h = relu((relu((A@W1)*a1+b1_)@W2)+b2_) +
// fused pool. Single 69.6KB LDS buffer: [As 128x136 | Ws 128x136] (ushort),
// whole buffer reused as float[128][132] for the pooling stash (all GEMM
// reads complete first). Wave handles 32 rows = 2 MFMA sub-tiles of 16.
// ---------------------------------------------------------------------------
__global__ __launch_bounds__(256) void layer_fused(const unsigned short* __restrict__ A,
                                                   const unsigned short* __restrict__ Wt1,
                                                   const unsigned short* __restrict__ Wt2,
                                                   const float* __restrict__ ea1,
                                                   const float* __restrict__ eb1,
                                                   const float* __restrict__ ea2,
                                                   const float* __restrict__ eb2,
                                                   const int* __restrict__ batch,
                                                   float* __restrict__ pooled, int loff,
                                                   unsigned short* __restrict__ outh, int n) {
    __shared__ __align__(16) char shraw[2 * 128 * 136 * 2];   // 69632 B
    unsigned short (*As)[136] = (unsigned short (*)[136])shraw;
    unsigned short (*Ws)[136] = (unsigned short (*)[136])(shraw + 128 * 136 * 2);
    __shared__ int bgsh[128];
    int tid = threadIdx.x;
    int row0 = blockIdx.x * 128;
    int wave = tid >> 6, lane = tid & 63;
    int m0 = wave * 32;
    int lrow = lane & 15, lq = lane >> 4;

    // stage A (128x128 bf16): 2048 ushort8 chunks, 8/thread
    #pragma unroll
    for (int i = 0; i < 8; ++i) {
        int idx = tid + i * 256;
        int r = idx >> 4, c = (idx & 15) * 8;
        ushort8 v = (ushort8)0;
        if (row0 + r < n) v = *(const ushort8*)&A[(size_t)(row0 + r) * D_FEAT + c];
        *(ushort8*)&As[r][c] = v;
    }
    // stage Wt1
    #pragma unroll
    for (int i = 0; i < 8; ++i) {
        int idx = tid + i * 256;
        int r = idx >> 4, c = (idx & 15) * 8;
        *(ushort8*)&Ws[r][c] = *(const ushort8*)&Wt1[(size_t)r * D_FEAT + c];
    }
    if (tid < 128)
        bgsh[tid] = (row0 + tid < n) ? batch[row0 + tid] : -1;

    // prefetch Wt2 into registers — drains while GEMM1 runs
    ushort8 w2reg[8];
    #pragma unroll
    for (int i = 0; i < 8; ++i) {
        int idx = tid + i * 256;
        int r = idx >> 4, c = (idx & 15) * 8;
        w2reg[i] = *(const ushort8*)&Wt2[(size_t)r * D_FEAT + c];
    }
    __syncthreads();

    // ---- GEMM 1 (2 sub-tiles of 16 rows per wave) ----
    f32x4 acc[2][8] = {};
    #pragma unroll
    for (int s = 0; s < 2; ++s) {
        #pragma unroll
        for (int t = 0; t < 4; ++t) {
            bf16x8 a = *(const bf16x8*)&As[m0 + s * 16 + lrow][t * 32 + lq * 8];
            #pragma unroll
            for (int nt = 0; nt < 8; ++nt) {
                bf16x8 b = *(const bf16x8*)&Ws[nt * 16 + lrow][t * 32 + lq * 8];
                acc[s][nt] = __builtin_amdgcn_mfma_f32_16x16x32_bf16(a, b, acc[s][nt], 0, 0, 0);
            }
        }
    }
    __syncthreads();

    // epilogue 1 -> z (bf16) into As; store prefetched Wt2 into Ws
    #pragma unroll
    for (int s = 0; s < 2; ++s) {
        #pragma unroll
        for (int nt = 0; nt < 8; ++nt) {
            int col = nt * 16 + lrow;
            float al = ea1[col], be = eb1[col];
            #pragma unroll
            for (int r = 0; r < 4; ++r) {
                float v = fmaxf(fmaf(acc[s][nt][r], al, be), 0.f);
                As[m0 + s * 16 + lq * 4 + r][col] = f2bf(v);
            }
        }
    }
    #pragma unroll
    for (int i = 0; i < 8; ++i) {
        int idx = tid + i * 256;
        int r = idx >> 4, c = (idx & 15) * 8;
        *(ushort8*)&Ws[r][c] = w2reg[i];
    }
    __syncthreads();

    // ---- GEMM 2 ----
    f32x4 acc2[2][8] = {};
    #pragma unroll
    for (int s = 0; s < 2; ++s) {
        #pragma unroll
        for (int t = 0; t < 4; ++t) {
            bf16x8 a = *(const bf16x8*)&As[m0 + s * 16 + lrow][t * 32 + lq * 8];
            #pragma unroll
            for (int nt = 0; nt < 8; ++nt) {
                bf16x8 b = *(const bf16x8*)&Ws[nt * 16 + lrow][t * 32 + lq * 8];
                acc2[s][nt] = __builtin_amdgcn_mfma_f32_16x16x32_bf16(a, b, acc2[s][nt], 0, 0, 0);
            }
        }
    }

    // epilogue 2 -> global h (skipped on last layer: dead write)
    if (outh) {
        #pragma unroll
        for (int s = 0; s < 2; ++s) {
            #pragma unroll
            for (int nt = 0; nt < 8; ++nt) {
                int col = nt * 16 + lrow;
                float al = ea2[col], be = eb2[col];
                #pragma unroll
                for (int r = 0; r < 4; ++r) {
                    int grow = row0 + m0 + s * 16 + lq * 4 + r;
                    if (grow < n) {
                        float v = fmaxf(fmaf(acc2[s][nt][r], al, be), 0.f);
                        outh[(size_t)grow * D_FEAT + col] = f2bf(v);
                    }
                }
            }
        }
    }

    // ---- fused pooling: alias whole LDS as float[128][132] ----
    __syncthreads();                       // all GEMM2 reads of As/Ws done
    float (*P)[132] = (float (*)[132])shraw;    // 128*132*4 = 67584 <= 69632
    #pragma unroll
    for (int s = 0; s < 2; ++s) {
        #pragma unroll
        for (int nt = 0; nt < 8; ++nt) {
            int col = nt * 16 + lrow;
            float al = ea2[col], be = eb2[col];
            #pragma unroll
            for (int r = 0; r < 4; ++r) {
                int lr = m0 + s * 16 + lq * 4 + r;
                float v = fmaxf(fmaf(acc2[s][nt][r], al, be), 0.f);
                P[lr][col] = bf2f(f2bf(v));   // match bf16-rounded h
            }
        }
    }
    __syncthreads();

    int c = tid & 127, half = tid >> 7;    // 2 halves x 64 rows each
    int rbeg = half * 64, rend = rbeg + 64;
    int cur = -1; float sum = 0.f;
    for (int r = rbeg; r < rend; ++r) {
        int g = bgsh[r];                   // uniform across the 128 col-threads
        if (g != cur) {
            if (cur >= 0) atomicAdd(&pooled[(size_t)cur * POOL_DIM + loff + c], sum);
            cur = g; sum = 0.f;
        }
        if (g >= 0) sum += P[r][c];
    }
    if (cur >= 0) atomicAdd(&pooled[(size_t)cur * POOL_DIM + loff + c], sum);
}

// ---------------------------------------------------------------------------
// Fused MLP head: 128 blocks x 384 threads, 4 graphs/block. fc1 exactly as
// r12 (coalesced W1, graphs in registers, k ascending) -> f1 in LDS -> fc2
// by threads 0..39 (full-K from LDS, k ascending: bitwise-same as r12).
// ---------------------------------------------------------------------------
__global__ __launch_bounds__(384) void head_kernel(const float* __restrict__ pooled,
                                                   const float* __restrict__ W1,
                                                   const float* __restrict__ b1v,
                                                   const float* __restrict__ W2,
                                                   const float* __restrict__ b2v,
                                                   float* __restrict__ out) {
    __shared__ float f1[4][POOL_DIM];
    int j = threadIdx.x;                   // 0..383
    int g0 = blockIdx.x * 4;
    const float* pr = pooled + (size_t)g0 * POOL_DIM;
    float bb = b1v[j];
    float s0 = bb, s1 = bb, s2 = bb, s3 = bb;
    for (int k0 = 0; k0 < POOL_DIM; k0 += 8) {
        float w[8];
        #pragma unroll
        for (int i = 0; i < 8; ++i)
            w[i] = W1[(size_t)(k0 + i) * POOL_DIM + j];
        #pragma unroll
        for (int i = 0; i < 8; ++i) {
            int k = k0 + i;
            s0 = fmaf(pr[k],                w[i], s0);
            s1 = fmaf(pr[POOL_DIM + k],     w[i], s1);
            s2 = fmaf(pr[2 * POOL_DIM + k], w[i], s2);
            s3 = fmaf(pr[3 * POOL_DIM + k], w[i], s3);
        }
    }
    f1[0][j] = fmaxf(s0, 0.f);
    f1[1][j] = fmaxf(s1, 0.f);
    f1[2][j] = fmaxf(s2, 0.f);
    f1[3][j] = fmaxf(s3, 0.f);
    __syncthreads();
    if (j < 4 * N_CLASSES) {
        int g = j / N_CLASSES, c = j % N_CLASSES;
        float s = b2v[c];
        for (int k = 0; k < POOL_DIM; ++k)
            s = fmaf(f1[g][k], W2[(size_t)k * N_CLASSES + c], s);
        out[(size_t)(g0 + g) * N_CLASSES + c] = s;
    }
}

// ---------------------------------------------------------------------------
extern "C" void kernel_launch(void* const* d_in, const int* in_sizes, int n_in,
                              void* d_out, int out_size, void* d_ws, size_t ws_size,
                              hipStream_t stream) {
    const float* x      = (const float*)d_in[0];
    const int*   ei     = (const int*)  d_in[1];
    const int*   batch  = (const int*)  d_in[2];
    const float* W1     = (const float*)d_in[3];
    const float* b1     = (const float*)d_in[4];
    const float* gamma  = (const float*)d_in[5];
    const float* beta   = (const float*)d_in[6];
    const float* rm     = (const float*)d_in[7];
    const float* rv     = (const float*)d_in[8];
    const float* W2     = (const float*)d_in[9];
    const float* b2     = (const float*)d_in[10];
    const float* lin1W  = (const float*)d_in[11];
    const float* lin1b  = (const float*)d_in[12];
    const float* lin2W  = (const float*)d_in[13];
    const float* lin2b  = (const float*)d_in[14];
    float* out = (float*)d_out;

    const int N = in_sizes[0] / D_FEAT;   // 50000
    const int E = in_sizes[1] / 2;        // 800000

    char* ws = (char*)d_ws;
    auto carve = [&](size_t bytes) {
        char* p = ws;
        ws += (bytes + 255) & ~(size_t)255;
        return p;
    };
    int*   cursor    = (int*)  carve((size_t)N * 4);
    int*   cnts      = (int*)  carve((size_t)NBINS * 256 * 4);
    int*   bucket    = (int*)  carve((size_t)N * CAP * 4);
    int2*  pairs     = (int2*) carve((size_t)NBINS * 256 * SLABCAP * 8);
    float* ea        = (float*)carve((size_t)2 * N_LAYERS * D_FEAT * 4);
    float* eb        = (float*)carve((size_t)2 * N_LAYERS * D_FEAT * 4);
    unsigned short* Wt   = (unsigned short*)carve((size_t)2 * N_LAYERS * D_FEAT * D_FEAT * 2);
    unsigned short* xb   = (unsigned short*)carve((size_t)N * D_FEAT * 2);
    unsigned short* ybuf = (unsigned short*)carve((size_t)N * D_FEAT * 2);
    unsigned short* hbuf = (unsigned short*)carve((size_t)N * D_FEAT * 2);
    float* pooled    = (float*)carve((size_t)N_GRAPHS * POOL_DIM * 4);

    // merged setup grid layout
    const int n4 = N * D_FEAT / 4;
    const int B0 = (n4 + 255) / 256;                            // cvt_x
    const int B1 = B0 + 24;                                     // cvt_w: 6 slots x 4 tiles
    const int B2 = B1 + 2;                                      // prep
    const int B3 = B2 + (N + 255) / 256;                        // cursor zero
    const int B4 = B3 + (N_GRAPHS * POOL_DIM + 255) / 256;      // pooled zero
    const int B5 = B4 + 256;                                    // bin

    setup_kernel<<<B5, 256, 0, stream>>>(x, xb, W1, W2, Wt, b1, gamma, beta,
                                         rm, rv, b2, ea, eb, cursor, pooled,
                                         ei, pairs, cnts, E,
                                         N, n4, B0, B1, B2, B3, B4);
    fill_v3<<<8 * 64, 256, 0, stream>>>(pairs, cnts, cursor, bucket);

    const unsigned short* hprev = xb;
    for (int l = 0; l < N_LAYERS; ++l) {
        agg_kernel<<<(N + 7) / 8, 256, 0, stream>>>(hprev, cursor, bucket, ybuf, N);
        unsigned short* outh = (l == N_LAYERS - 1) ? nullptr : hbuf;
        layer_fused<<<(N + 127) / 128, 256, 0, stream>>>(ybuf,
                      Wt + (size_t)(2 * l) * D_FEAT * D_FEAT,
                      Wt + (size_t)(2 * l + 1) * D_FEAT * D_FEAT,
                      ea + (size_t)(2 * l) * D_FEAT,
                      eb + (size_t)(2 * l) * D_FEAT,
                      ea + (size_t)(2 * l + 1) * D_FEAT,
                      eb + (size_t)(2 * l + 1) * D_FEAT,
                      batch, pooled, l * D_FEAT, outh, N);
        hprev = hbuf;
    }
    head_kernel<<<N_GRAPHS / 4, 384, 0, stream>>>(pooled, lin1W, lin1b, lin2W, lin2b, out);
}

// Round 14
// 341.198 us; speedup vs baseline: 1.1487x; 1.1487x over previous
//
#include <hip/hip_runtime.h>
#include <hip/hip_bf16.h>

// Problem constants: N=50000, E=800000, G=512, L=3, D=128
#define D_FEAT 128
#define N_GRAPHS 512
#define N_LAYERS 3
#define POOL_DIM (N_LAYERS * D_FEAT)   // 384
#define N_CLASSES 10
#define BN_EPS 1e-5f
#define CAP 64                         // fixed bucket capacity; P(deg>64) ~ 2e-18
#define NBINS 8
#define SLABCAP 768                    // per (bin,block) slab; mean 390, 13.5 sigma

// LESSON (r7): gather is latency-bound -> max occupancy + tiny footprint;
// GEMM needs 52KB LDS. Keep them separate kernels.
// LESSON (r3/r8): scatter regions written at <64B granularity by blocks on
// multiple XCDs get ~16x writeback amplification. Private slabs / XCD
// partitioning fix it.
// LESSON (r10): agg in-flight rows/SIMD is pinned by the VGPR occupancy
// cliff -> agg is at its LLC-gather floor; stop tuning it.
// LESSON (r11): never shrink a small kernel's grid below ~256 blocks to buy
// data reuse — 64-block head ran at 2.5% occupancy, 70us. Latency-hiding,
// not traffic, is binding for sub-10us kernels.
// LESSON (r13): 128-row tile (70KB LDS, <=2 blk/CU, 391-block grid) DROPPED
// occupancy to 7% and doubled layer time to 51us. "GEMM tolerates low
// occupancy" only holds for long K-loops; for short staging-heavy kernels
// keep >=3 blocks/CU. The 64-row/52KB tile is the sweet spot here.

typedef __attribute__((ext_vector_type(8))) short bf16x8;
typedef __attribute__((ext_vector_type(8))) unsigned short ushort8;
typedef __attribute__((ext_vector_type(4))) float f32x4;

__device__ __forceinline__ unsigned short f2bf(float f) {
    unsigned u = __builtin_bit_cast(unsigned, f);
    u += 0x7FFFu + ((u >> 16) & 1u);          // round-to-nearest-even
    return (unsigned short)(u >> 16);
}
__device__ __forceinline__ float bf2f(unsigned short h) {
    unsigned u = ((unsigned)h) << 16;
    return __builtin_bit_cast(float, u);
}
__device__ __forceinline__ float bf_lo(unsigned u) {
    return __builtin_bit_cast(float, u << 16);
}
__device__ __forceinline__ float bf_hi(unsigned u) {
    return __builtin_bit_cast(float, u & 0xffff0000u);
}

// ---------------------------------------------------------------------------
// Merged setup: cvt_x | cvt_w(LDS-transpose tiles) | prep | zero cursor |
// zero pooled | BIN (radix partition into per-(bin,block) private slabs).
// ---------------------------------------------------------------------------
__global__ __launch_bounds__(256) void setup_kernel(
        const float* __restrict__ x, unsigned short* __restrict__ xb,
        const float* __restrict__ W1, const float* __restrict__ W2,
        unsigned short* __restrict__ Wt,
        const float* __restrict__ b1, const float* __restrict__ gamma,
        const float* __restrict__ beta, const float* __restrict__ rm,
        const float* __restrict__ rv, const float* __restrict__ b2,
        float* __restrict__ ea, float* __restrict__ eb,
        int* __restrict__ cursor, float* __restrict__ pooled,
        const int* __restrict__ ei, int2* __restrict__ pairs,
        int* __restrict__ cnts, int E,
        int N, int n4, int B0, int B1, int B2, int B3, int B4) {
    int b = blockIdx.x, tid = threadIdx.x;
    if (b < B0) {                                     // cvt_x: fp32 -> bf16
        int i = b * 256 + tid;
        if (i < n4) {
            float4 v = ((const float4*)x)[i];
            ushort4 o;
            o.x = f2bf(v.x); o.y = f2bf(v.y); o.z = f2bf(v.z); o.w = f2bf(v.w);
            ((ushort4*)xb)[i] = o;
        }
    } else if (b < B1) {                              // cvt_w: coalesced transpose
        __shared__ float tile[64][65];
        int t = b - B0;                               // 0..23
        int slot = t >> 2;                            // 6 slots
        int r0 = ((t >> 1) & 1) * 64;                 // k-block in W rows
        int c0 = (t & 1) * 64;                        // n-block in W cols
        int l = slot >> 1;
        const float* W = (slot & 1) ? W2 : W1;
        const float* Wb = W + (size_t)l * D_FEAT * D_FEAT;
        int rr = tid >> 2, cc4 = (tid & 3) * 16;
        #pragma unroll
        for (int j = 0; j < 16; ++j)
            tile[rr][cc4 + j] = Wb[(size_t)(r0 + rr) * D_FEAT + c0 + cc4 + j];
        __syncthreads();
        int nn = tid >> 2, kk4 = (tid & 3) * 16;
        unsigned short* Wo = Wt + (size_t)slot * D_FEAT * D_FEAT;
        #pragma unroll
        for (int j = 0; j < 16; ++j)
            Wo[(size_t)(c0 + nn) * D_FEAT + r0 + kk4 + j] = f2bf(tile[kk4 + j][nn]);
    } else if (b < B2) {                              // prep: fold BN+bias
        int i = (b - B1) * 256 + tid;
        if (i < N_LAYERS * D_FEAT) {
            int l = i >> 7, c = i & 127;
            float s = gamma[i] * rsqrtf(rv[i] + BN_EPS);
            ea[(2 * l) * D_FEAT + c] = s;
            eb[(2 * l) * D_FEAT + c] = (b1[i] - rm[i]) * s + beta[i];
            ea[(2 * l + 1) * D_FEAT + c] = 1.0f;
            eb[(2 * l + 1) * D_FEAT + c] = b2[i];
        }
    } else if (b < B3) {                              // zero cursor
        int i = (b - B2) * 256 + tid;
        if (i < N) cursor[i] = 0;
    } else if (b < B4) {                              // zero pooled
        int i = (b - B3) * 256 + tid;
        if (i < N_GRAPHS * POOL_DIM) pooled[i] = 0.f;
    } else {                                          // bin: radix partition
        __shared__ int loc[NBINS];
        int bb = b - B4;                              // 0..255
        int per = (E + 255) / 256;
        int e0 = bb * per;
        int e1 = e0 + per; if (e1 > E) e1 = E;
        int span = (N + NBINS - 1) / NBINS;
        if (tid < NBINS) loc[tid] = 0;
        __syncthreads();
        for (int e = e0 + tid; e < e1; e += 256) {
            int dst = ei[E + e];
            int src = ei[e];
            int bin = dst / span;
            int p = atomicAdd(&loc[bin], 1);
            if (p < SLABCAP)
                pairs[((size_t)(bin * 256 + bb)) * SLABCAP + p] = make_int2(src, dst);
        }
        __syncthreads();
        if (tid < NBINS)
            cnts[tid * 256 + bb] = loc[tid];
    }
}

// ---------------------------------------------------------------------------
// Fill: blockIdx%8 = dst-range = XCD (CP round-robin): cursor atomics +
// bucket scatter stay in one XCD's L2. Dense slab reads.
// ---------------------------------------------------------------------------
__global__ __launch_bounds__(256) void fill_v3(const int2* __restrict__ pairs,
                                               const int* __restrict__ cnts,
                                               int* __restrict__ cursor,
                                               int* __restrict__ bucket) {
    int r = blockIdx.x & 7;
    int chunk = blockIdx.x >> 3;              // 0..63
    #pragma unroll
    for (int s = 0; s < 4; ++s) {
        int blk = chunk * 4 + s;              // 0..255
        int cnt = cnts[r * 256 + blk];
        if (cnt > SLABCAP) cnt = SLABCAP;
        const int2* slab = pairs + (size_t)(r * 256 + blk) * SLABCAP;
        for (int p = threadIdx.x; p < cnt; p += 256) {
            int2 pr = slab[p];
            int pos = atomicAdd(&cursor[pr.y], 1);
            if (pos < CAP) bucket[(size_t)pr.y * CAP + pos] = pr.x;
        }
    }
}

// ---------------------------------------------------------------------------
// Aggregation: one wave per TWO nodes, zero LDS, software-pipelined chunks;
// self-row loads hoisted ahead of the loop. (At the LLC-gather floor — r10.)
// ---------------------------------------------------------------------------
__global__ __launch_bounds__(256) void agg_kernel(const unsigned short* __restrict__ hprev,
                                                  const int* __restrict__ deg,
                                                  const int* __restrict__ bucket,
                                                  unsigned short* __restrict__ y, int n) {
    int wave = threadIdx.x >> 6, lane = threadIdx.x & 63;
    int n0 = (blockIdx.x * 4 + wave) * 2;
    if (n0 >= n) return;
    int n1 = n0 + 1;
    bool v1 = (n1 < n);
    int d0 = deg[n0]; if (d0 > CAP) d0 = CAP;
    int d1 = v1 ? deg[n1] : 0; if (d1 > CAP) d1 = CAP;
    int grp = lane >> 4, sub = lane & 15;
    const uint4* hp = (const uint4*)hprev;

    int idx0 = bucket[(size_t)n0 * CAP + lane];
    int idx1 = v1 ? bucket[(size_t)n1 * CAP + lane] : 0;

    uint4 s0v = hp[(size_t)n0 * 16 + sub];
    uint4 s1v = v1 ? hp[(size_t)n1 * 16 + sub] : make_uint4(0u, 0u, 0u, 0u);

    float a0[8] = {0.f,0.f,0.f,0.f,0.f,0.f,0.f,0.f};
    float a1[8] = {0.f,0.f,0.f,0.f,0.f,0.f,0.f,0.f};
    int dmax = d0 > d1 ? d0 : d1;

    auto issue = [&](int t, bool (&p0)[4], bool (&p1)[4],
                     uint4 (&w0)[4], uint4 (&w1)[4]) {
        #pragma unroll
        for (int q = 0; q < 4; ++q) {
            int e = t + q * 4 + grp;
            int s0 = __shfl(idx0, e & 63);
            int s1 = __shfl(idx1, e & 63);
            p0[q] = e < d0;
            p1[q] = e < d1;
            int r0 = p0[q] ? s0 : n0;
            int r1 = p1[q] ? s1 : n0;
            w0[q] = hp[(size_t)r0 * 16 + sub];
            w1[q] = hp[(size_t)r1 * 16 + sub];
        }
    };
    auto accum = [&](bool (&p0)[4], bool (&p1)[4],
                     uint4 (&w0)[4], uint4 (&w1)[4]) {
        #pragma unroll
        for (int q = 0; q < 4; ++q) {
            if (p0[q]) {
                uint4 v = w0[q];
                a0[0] += bf_lo(v.x); a0[1] += bf_hi(v.x);
                a0[2] += bf_lo(v.y); a0[3] += bf_hi(v.y);
                a0[4] += bf_lo(v.z); a0[5] += bf_hi(v.z);
                a0[6] += bf_lo(v.w); a0[7] += bf_hi(v.w);
            }
            if (p1[q]) {
                uint4 v = w1[q];
                a1[0] += bf_lo(v.x); a1[1] += bf_hi(v.x);
                a1[2] += bf_lo(v.y); a1[3] += bf_hi(v.y);
                a1[4] += bf_lo(v.z); a1[5] += bf_hi(v.z);
                a1[6] += bf_lo(v.w); a1[7] += bf_hi(v.w);
            }
        }
    };

    if (dmax > 0) {
        bool cp0[4], cp1[4];
        uint4 cw0[4], cw1[4];
        issue(0, cp0, cp1, cw0, cw1);
        for (int t = 16; t < dmax; t += 16) {
            bool np0[4], np1[4];
            uint4 nw0[4], nw1[4];
            issue(t, np0, np1, nw0, nw1);
            accum(cp0, cp1, cw0, cw1);
            #pragma unroll
            for (int q = 0; q < 4; ++q) {
                cp0[q] = np0[q]; cp1[q] = np1[q];
                cw0[q] = nw0[q]; cw1[q] = nw1[q];
            }
        }
        accum(cp0, cp1, cw0, cw1);
    }

    #pragma unroll
    for (int j = 0; j < 8; ++j) {
        a0[j] += __shfl_xor(a0[j], 16);
        a0[j] += __shfl_xor(a0[j], 32);
        a1[j] += __shfl_xor(a1[j], 16);
        a1[j] += __shfl_xor(a1[j], 32);
    }

    a0[0] += bf_lo(s0v.x); a0[1] += bf_hi(s0v.x);
    a0[2] += bf_lo(s0v.y); a0[3] += bf_hi(s0v.y);
    a0[4] += bf_lo(s0v.z); a0[5] += bf_hi(s0v.z);
    a0[6] += bf_lo(s0v.w); a0[7] += bf_hi(s0v.w);
    if (v1) {
        a1[0] += bf_lo(s1v.x); a1[1] += bf_hi(s1v.x);
        a1[2] += bf_lo(s1v.y); a1[3] += bf_hi(s1v.y);
        a1[4] += bf_lo(s1v.z); a1[5] += bf_hi(s1v.z);
        a1[6] += bf_lo(s1v.w); a1[7] += bf_hi(s1v.w);
    }

    if (grp == 0) {
        uint4 o;
        o.x = (unsigned)f2bf(a0[0]) | ((unsigned)f2bf(a0[1]) << 16);
        o.y = (unsigned)f2bf(a0[2]) | ((unsigned)f2bf(a0[3]) << 16);
        o.z = (unsigned)f2bf(a0[4]) | ((unsigned)f2bf(a0[5]) << 16);
        o.w = (unsigned)f2bf(a0[6]) | ((unsigned)f2bf(a0[7]) << 16);
        ((uint4*)y)[(size_t)n0 * 16 + sub] = o;
        if (v1) {
            uint4 p;
            p.x = (unsigned)f2bf(a1[0]) | ((unsigned)f2bf(a1[1]) << 16);
            p.y = (unsigned)f2bf(a1[2]) | ((unsigned)f2bf(a1[3]) << 16);
            p.z = (unsigned)f2bf(a1[4]) | ((unsigned)f2bf(a1[5]) << 16);
            p.w = (unsigned)f2bf(a1[6]) | ((unsigned)f2bf(a1[7]) << 16);
            ((uint4*)y)[(size_t)n1 * 16 + sub] = p;
        }
    }
}

// ---------------------------------------------------------------------------
// Fused layer GEMM (r12 64-row tile — known-good): h = relu((relu((A@W1)*a1
// +b1_)@W2)+b2_) + fused pool. Wt2 prefetched into registers before GEMM1.
// outh==NULL on the last layer (dead write).
// ---------------------------------------------------------------------------
__global__ __launch_bounds__(256) void layer_fused(const unsigned short* __restrict__ A,
                                                   const unsigned short* __restrict__ Wt1,
                                                   const unsigned short* __restrict__ Wt2,
                                                   const float* __restrict__ ea1,
                                                   const float* __restrict__ eb1,
                                                   const float* __restrict__ ea2,
                                                   const float* __restrict__ eb2,
                                                   const int* __restrict__ batch,
                                                   float* __restrict__ pooled, int loff,
                                                   unsigned short* __restrict__ outh, int n) {
    __shared__ unsigned short As[64][136];
    __shared__ unsigned short Ws[128][136];
    __shared__ int bgsh[64];
    int tid = threadIdx.x;
    int row0 = blockIdx.x * 64;
    int wave = tid >> 6, lane = tid & 63;
    int m0 = wave * 16;
    int lrow = lane & 15, lq = lane >> 4;

    #pragma unroll
    for (int i = 0; i < 4; ++i) {
        int idx = tid + i * 256;
        int r = idx >> 4, c = (idx & 15) * 8;
        ushort8 v = (ushort8)0;
        if (row0 + r < n) v = *(const ushort8*)&A[(size_t)(row0 + r) * D_FEAT + c];
        *(ushort8*)&As[r][c] = v;
    }
    #pragma unroll
    for (int i = 0; i < 8; ++i) {
        int idx = tid + i * 256;
        int r = idx >> 4, c = (idx & 15) * 8;
        *(ushort8*)&Ws[r][c] = *(const ushort8*)&Wt1[(size_t)r * D_FEAT + c];
    }
    if (tid < 64)
        bgsh[tid] = (row0 + tid < n) ? batch[row0 + tid] : -1;

    ushort8 w2reg[8];
    #pragma unroll
    for (int i = 0; i < 8; ++i) {
        int idx = tid + i * 256;
        int r = idx >> 4, c = (idx & 15) * 8;
        w2reg[i] = *(const ushort8*)&Wt2[(size_t)r * D_FEAT + c];
    }
    __syncthreads();

    // ---- GEMM 1 ----
    f32x4 acc[8] = {};
    #pragma unroll
    for (int t = 0; t < 4; ++t) {
        bf16x8 a = *(const bf16x8*)&As[m0 + lrow][t * 32 + lq * 8];
        #pragma unroll
        for (int nt = 0; nt < 8; ++nt) {
            bf16x8 b = *(const bf16x8*)&Ws[nt * 16 + lrow][t * 32 + lq * 8];
            acc[nt] = __builtin_amdgcn_mfma_f32_16x16x32_bf16(a, b, acc[nt], 0, 0, 0);
        }
    }
    __syncthreads();

    #pragma unroll
    for (int nt = 0; nt < 8; ++nt) {
        int col = nt * 16 + lrow;
        float al = ea1[col], be = eb1[col];
        #pragma unroll
        for (int r = 0; r < 4; ++r) {
            float v = fmaxf(fmaf(acc[nt][r], al, be), 0.f);
            As[m0 + lq * 4 + r][col] = f2bf(v);
        }
    }
    #pragma unroll
    for (int i = 0; i < 8; ++i) {
        int idx = tid + i * 256;
        int r = idx >> 4, c = (idx & 15) * 8;
        *(ushort8*)&Ws[r][c] = w2reg[i];
    }
    __syncthreads();

    // ---- GEMM 2 ----
    f32x4 acc2[8] = {};
    #pragma unroll
    for (int t = 0; t < 4; ++t) {
        bf16x8 a = *(const bf16x8*)&As[m0 + lrow][t * 32 + lq * 8];
        #pragma unroll
        for (int nt = 0; nt < 8; ++nt) {
            bf16x8 b = *(const bf16x8*)&Ws[nt * 16 + lrow][t * 32 + lq * 8];
            acc2[nt] = __builtin_amdgcn_mfma_f32_16x16x32_bf16(a, b, acc2[nt], 0, 0, 0);
        }
    }

    if (outh) {
        #pragma unroll
        for (int nt = 0; nt < 8; ++nt) {
            int col = nt * 16 + lrow;
            float al = ea2[col], be = eb2[col];
            #pragma unroll
            for (int r = 0; r < 4; ++r) {
                int grow = row0 + m0 + lq * 4 + r;
                if (grow < n) {
                    float v = fmaxf(fmaf(acc2[nt][r], al, be), 0.f);
                    outh[(size_t)grow * D_FEAT + col] = f2bf(v);
                }
            }
        }
    }

    // ---- fused pooling ----
    __syncthreads();                       // all GEMM2 reads of Ws done
    float* Wsf = (float*)Ws;               // 64 x (stride 132) floats
    #pragma unroll
    for (int nt = 0; nt < 8; ++nt) {
        int col = nt * 16 + lrow;
        float al = ea2[col], be = eb2[col];
        #pragma unroll
        for (int r = 0; r < 4; ++r) {
            int lr = m0 + lq * 4 + r;
            float v = fmaxf(fmaf(acc2[nt][r], al, be), 0.f);
            Wsf[lr * 132 + col] = bf2f(f2bf(v));   // match bf16-rounded h
        }
    }
    __syncthreads();

    int c = tid & 127, half = tid >> 7;    // 2 halves x 32 rows each
    int rbeg = half * 32, rend = rbeg + 32;
    int cur = -1; float sum = 0.f;
    for (int r = rbeg; r < rend; ++r) {
        int g = bgsh[r];
        if (g != cur) {
            if (cur >= 0) atomicAdd(&pooled[(size_t)cur * POOL_DIM + loff + c], sum);
            cur = g; sum = 0.f;
        }
        if (g >= 0) sum += Wsf[r * 132 + c];
    }
    if (cur >= 0) atomicAdd(&pooled[(size_t)cur * POOL_DIM + loff + c], sum);
}

// ---------------------------------------------------------------------------
// Fused MLP head: 128 blocks x 384 threads, 4 graphs/block. fc1 exactly as
// r12 (coalesced W1, graphs in registers, k ascending) -> f1 in LDS -> fc2
// by threads 0..39 (full-K from LDS, k ascending: bitwise-same as r12).
// ---------------------------------------------------------------------------
__global__ __launch_bounds__(384) void head_kernel(const float* __restrict__ pooled,
                                                   const float* __restrict__ W1,
                                                   const float* __restrict__ b1v,
                                                   const float* __restrict__ W2,
                                                   const float* __restrict__ b2v,
                                                   float* __restrict__ out) {
    __shared__ float f1[4][POOL_DIM];
    int j = threadIdx.x;                   // 0..383
    int g0 = blockIdx.x * 4;
    const float* pr = pooled + (size_t)g0 * POOL_DIM;
    float bb = b1v[j];
    float s0 = bb, s1 = bb, s2 = bb, s3 = bb;
    for (int k0 = 0; k0 < POOL_DIM; k0 += 8) {
        float w[8];
        #pragma unroll
        for (int i = 0; i < 8; ++i)
            w[i] = W1[(size_t)(k0 + i) * POOL_DIM + j];
        #pragma unroll
        for (int i = 0; i < 8; ++i) {
            int k = k0 + i;
            s0 = fmaf(pr[k],                w[i], s0);
            s1 = fmaf(pr[POOL_DIM + k],     w[i], s1);
            s2 = fmaf(pr[2 * POOL_DIM + k], w[i], s2);
            s3 = fmaf(pr[3 * POOL_DIM + k], w[i], s3);
        }
    }
    f1[0][j] = fmaxf(s0, 0.f);
    f1[1][j] = fmaxf(s1, 0.f);
    f1[2][j] = fmaxf(s2, 0.f);
    f1[3][j] = fmaxf(s3, 0.f);
    __syncthreads();
    if (j < 4 * N_CLASSES) {
        int g = j / N_CLASSES, c = j % N_CLASSES;
        float s = b2v[c];
        for (int k = 0; k < POOL_DIM; ++k)
            s = fmaf(f1[g][k], W2[(size_t)k * N_CLASSES + c], s);
        out[(size_t)(g0 + g) * N_CLASSES + c] = s;
    }
}

// ---------------------------------------------------------------------------
extern "C" void kernel_launch(void* const* d_in, const int* in_sizes, int n_in,
                              void* d_out, int out_size, void* d_ws, size_t ws_size,
                              hipStream_t stream) {
    const float* x      = (const float*)d_in[0];
    const int*   ei     = (const int*)  d_in[1];
    const int*   batch  = (const int*)  d_in[2];
    const float* W1     = (const float*)d_in[3];
    const float* b1     = (const float*)d_in[4];
    const float* gamma  = (const float*)d_in[5];
    const float* beta   = (const float*)d_in[6];
    const float* rm     = (const float*)d_in[7];
    const float* rv     = (const float*)d_in[8];
    const float* W2     = (const float*)d_in[9];
    const float* b2     = (const float*)d_in[10];
    const float* lin1W  = (const float*)d_in[11];
    const float* lin1b  = (const float*)d_in[12];
    const float* lin2W  = (const float*)d_in[13];
    const float* lin2b  = (const float*)d_in[14];
    float* out = (float*)d_out;

    const int N = in_sizes[0] / D_FEAT;   // 50000
    const int E = in_sizes[1] / 2;        // 800000

    char* ws = (char*)d_ws;
    auto carve = [&](size_t bytes) {
        char* p = ws;
        ws += (bytes + 255) & ~(size_t)255;
        return p;
    };
    int*   cursor    = (int*)  carve((size_t)N * 4);
    int*   cnts      = (int*)  carve((size_t)NBINS * 256 * 4);
    int*   bucket    = (int*)  carve((size_t)N * CAP * 4);
    int2*  pairs     = (int2*) carve((size_t)NBINS * 256 * SLABCAP * 8);
    float* ea        = (float*)carve((size_t)2 * N_LAYERS * D_FEAT * 4);
    float* eb        = (float*)carve((size_t)2 * N_LAYERS * D_FEAT * 4);
    unsigned short* Wt   = (unsigned short*)carve((size_t)2 * N_LAYERS * D_FEAT * D_FEAT * 2);
    unsigned short* xb   = (unsigned short*)carve((size_t)N * D_FEAT * 2);
    unsigned short* ybuf = (unsigned short*)carve((size_t)N * D_FEAT * 2);
    unsigned short* hbuf = (unsigned short*)carve((size_t)N * D_FEAT * 2);
    float* pooled    = (float*)carve((size_t)N_GRAPHS * POOL_DIM * 4);

    // merged setup grid layout
    const int n4 = N * D_FEAT / 4;
    const int B0 = (n4 + 255) / 256;                            // cvt_x
    const int B1 = B0 + 24;                                     // cvt_w: 6 slots x 4 tiles
    const int B2 = B1 + 2;                                      // prep
    const int B3 = B2 + (N + 255) / 256;                        // cursor zero
    const int B4 = B3 + (N_GRAPHS * POOL_DIM + 255) / 256;      // pooled zero
    const int B5 = B4 + 256;                                    // bin

    setup_kernel<<<B5, 256, 0, stream>>>(x, xb, W1, W2, Wt, b1, gamma, beta,
                                         rm, rv, b2, ea, eb, cursor, pooled,
                                         ei, pairs, cnts, E,
                                         N, n4, B0, B1, B2, B3, B4);
    fill_v3<<<8 * 64, 256, 0, stream>>>(pairs, cnts, cursor, bucket);

    const unsigned short* hprev = xb;
    for (int l = 0; l < N_LAYERS; ++l) {
        agg_kernel<<<(N + 7) / 8, 256, 0, stream>>>(hprev, cursor, bucket, ybuf, N);
        unsigned short* outh = (l == N_LAYERS - 1) ? nullptr : hbuf;
        layer_fused<<<(N + 63) / 64, 256, 0, stream>>>(ybuf,
                      Wt + (size_t)(2 * l) * D_FEAT * D_FEAT,
                      Wt + (size_t)(2 * l + 1) * D_FEAT * D_FEAT,
                      ea + (size_t)(2 * l) * D_FEAT,
                      eb + (size_t)(2 * l) * D_FEAT,
                      ea + (size_t)(2 * l + 1) * D_FEAT,
                      eb + (size_t)(2 * l + 1) * D_FEAT,
                      batch, pooled, l * D_FEAT, outh, N);
        hprev = hbuf;
    }
    head_kernel<<<N_GRAPHS / 4, 384, 0, stream>>>(pooled, lin1W, lin1b, lin2W, lin2b, out);
}

// Round 15
// 322.170 us; speedup vs baseline: 1.2165x; 1.0591x over previous
//
#include <hip/hip_runtime.h>
#include <hip/hip_bf16.h>

// Problem constants: N=50000, E=800000, G=512, L=3, D=128
#define D_FEAT 128
#define N_GRAPHS 512
#define N_LAYERS 3
#define POOL_DIM (N_LAYERS * D_FEAT)   // 384
#define N_CLASSES 10
#define BN_EPS 1e-5f
#define CAP 64                         // fixed bucket capacity; P(deg>64) ~ 2e-18
#define NBINS 8
#define SLABCAP 768                    // per (bin,block) slab; mean 390, 13.5 sigma

// LESSON (r7): gather is latency-bound -> max occupancy + tiny footprint;
// GEMM needs 52KB LDS. Keep them separate kernels.
// LESSON (r3/r8): scatter regions written at <64B granularity by blocks on
// multiple XCDs get ~16x writeback amplification. Private slabs / XCD
// partitioning fix it.
// LESSON (r10): agg in-flight rows/SIMD is pinned by the VGPR occupancy
// cliff -> agg is at its LLC-gather floor; stop tuning it.
// LESSON (r11): never shrink a small kernel's grid below ~256 blocks to buy
// data reuse — latency-hiding, not traffic, binds sub-10us kernels.
// LESSON (r13): 128-row tile (70KB LDS, <=2 blk/CU) halved occupancy and
// doubled layer time. 64-row/52KB is the sweet spot; keep >=3 blocks/CU.
// r15: pooling moved from LDS stash (2 barriers + 33KB traffic) to wave
// shfl_xor reduction — layer_fused now has 3 barriers total.

typedef __attribute__((ext_vector_type(8))) short bf16x8;
typedef __attribute__((ext_vector_type(8))) unsigned short ushort8;
typedef __attribute__((ext_vector_type(4))) float f32x4;

__device__ __forceinline__ unsigned short f2bf(float f) {
    unsigned u = __builtin_bit_cast(unsigned, f);
    u += 0x7FFFu + ((u >> 16) & 1u);          // round-to-nearest-even
    return (unsigned short)(u >> 16);
}
__device__ __forceinline__ float bf2f(unsigned short h) {
    unsigned u = ((unsigned)h) << 16;
    return __builtin_bit_cast(float, u);
}
__device__ __forceinline__ float bf_lo(unsigned u) {
    return __builtin_bit_cast(float, u << 16);
}
__device__ __forceinline__ float bf_hi(unsigned u) {
    return __builtin_bit_cast(float, u & 0xffff0000u);
}

// ---------------------------------------------------------------------------
// Merged setup: cvt_x | cvt_w(LDS-transpose tiles) | prep | zero cursor |
// zero pooled | BIN (radix partition into per-(bin,block) private slabs).
// ---------------------------------------------------------------------------
__global__ __launch_bounds__(256) void setup_kernel(
        const float* __restrict__ x, unsigned short* __restrict__ xb,
        const float* __restrict__ W1, const float* __restrict__ W2,
        unsigned short* __restrict__ Wt,
        const float* __restrict__ b1, const float* __restrict__ gamma,
        const float* __restrict__ beta, const float* __restrict__ rm,
        const float* __restrict__ rv, const float* __restrict__ b2,
        float* __restrict__ ea, float* __restrict__ eb,
        int* __restrict__ cursor, float* __restrict__ pooled,
        const int* __restrict__ ei, int2* __restrict__ pairs,
        int* __restrict__ cnts, int E,
        int N, int n4, int B0, int B1, int B2, int B3, int B4) {
    int b = blockIdx.x, tid = threadIdx.x;
    if (b < B0) {                                     // cvt_x: fp32 -> bf16
        int i = b * 256 + tid;
        if (i < n4) {
            float4 v = ((const float4*)x)[i];
            ushort4 o;
            o.x = f2bf(v.x); o.y = f2bf(v.y); o.z = f2bf(v.z); o.w = f2bf(v.w);
            ((ushort4*)xb)[i] = o;
        }
    } else if (b < B1) {                              // cvt_w: coalesced transpose
        __shared__ float tile[64][65];
        int t = b - B0;                               // 0..23
        int slot = t >> 2;                            // 6 slots
        int r0 = ((t >> 1) & 1) * 64;                 // k-block in W rows
        int c0 = (t & 1) * 64;                        // n-block in W cols
        int l = slot >> 1;
        const float* W = (slot & 1) ? W2 : W1;
        const float* Wb = W + (size_t)l * D_FEAT * D_FEAT;
        int rr = tid >> 2, cc4 = (tid & 3) * 16;
        #pragma unroll
        for (int j = 0; j < 16; ++j)
            tile[rr][cc4 + j] = Wb[(size_t)(r0 + rr) * D_FEAT + c0 + cc4 + j];
        __syncthreads();
        int nn = tid >> 2, kk4 = (tid & 3) * 16;
        unsigned short* Wo = Wt + (size_t)slot * D_FEAT * D_FEAT;
        #pragma unroll
        for (int j = 0; j < 16; ++j)
            Wo[(size_t)(c0 + nn) * D_FEAT + r0 + kk4 + j] = f2bf(tile[kk4 + j][nn]);
    } else if (b < B2) {                              // prep: fold BN+bias
        int i = (b - B1) * 256 + tid;
        if (i < N_LAYERS * D_FEAT) {
            int l = i >> 7, c = i & 127;
            float s = gamma[i] * rsqrtf(rv[i] + BN_EPS);
            ea[(2 * l) * D_FEAT + c] = s;
            eb[(2 * l) * D_FEAT + c] = (b1[i] - rm[i]) * s + beta[i];
            ea[(2 * l + 1) * D_FEAT + c] = 1.0f;
            eb[(2 * l + 1) * D_FEAT + c] = b2[i];
        }
    } else if (b < B3) {                              // zero cursor
        int i = (b - B2) * 256 + tid;
        if (i < N) cursor[i] = 0;
    } else if (b < B4) {                              // zero pooled
        int i = (b - B3) * 256 + tid;
        if (i < N_GRAPHS * POOL_DIM) pooled[i] = 0.f;
    } else {                                          // bin: radix partition
        __shared__ int loc[NBINS];
        int bb = b - B4;                              // 0..255
        int per = (E + 255) / 256;
        int e0 = bb * per;
        int e1 = e0 + per; if (e1 > E) e1 = E;
        int span = (N + NBINS - 1) / NBINS;
        if (tid < NBINS) loc[tid] = 0;
        __syncthreads();
        for (int e = e0 + tid; e < e1; e += 256) {
            int dst = ei[E + e];
            int src = ei[e];
            int bin = dst / span;
            int p = atomicAdd(&loc[bin], 1);
            if (p < SLABCAP)
                pairs[((size_t)(bin * 256 + bb)) * SLABCAP + p] = make_int2(src, dst);
        }
        __syncthreads();
        if (tid < NBINS)
            cnts[tid * 256 + bb] = loc[tid];
    }
}

// ---------------------------------------------------------------------------
// Fill: blockIdx%8 = dst-range = XCD (CP round-robin): cursor atomics +
// bucket scatter stay in one XCD's L2. Dense slab reads.
// ---------------------------------------------------------------------------
__global__ __launch_bounds__(256) void fill_v3(const int2* __restrict__ pairs,
                                               const int* __restrict__ cnts,
                                               int* __restrict__ cursor,
                                               int* __restrict__ bucket) {
    int r = blockIdx.x & 7;
    int chunk = blockIdx.x >> 3;              // 0..63
    #pragma unroll
    for (int s = 0; s < 4; ++s) {
        int blk = chunk * 4 + s;              // 0..255
        int cnt = cnts[r * 256 + blk];
        if (cnt > SLABCAP) cnt = SLABCAP;
        const int2* slab = pairs + (size_t)(r * 256 + blk) * SLABCAP;
        for (int p = threadIdx.x; p < cnt; p += 256) {
            int2 pr = slab[p];
            int pos = atomicAdd(&cursor[pr.y], 1);
            if (pos < CAP) bucket[(size_t)pr.y * CAP + pos] = pr.x;
        }
    }
}

// ---------------------------------------------------------------------------
// Aggregation: one wave per TWO nodes, zero LDS, software-pipelined chunks;
// self-row loads hoisted ahead of the loop. (At the LLC-gather floor — r10.)
// ---------------------------------------------------------------------------
__global__ __launch_bounds__(256) void agg_kernel(const unsigned short* __restrict__ hprev,
                                                  const int* __restrict__ deg,
                                                  const int* __restrict__ bucket,
                                                  unsigned short* __restrict__ y, int n) {
    int wave = threadIdx.x >> 6, lane = threadIdx.x & 63;
    int n0 = (blockIdx.x * 4 + wave) * 2;
    if (n0 >= n) return;
    int n1 = n0 + 1;
    bool v1 = (n1 < n);
    int d0 = deg[n0]; if (d0 > CAP) d0 = CAP;
    int d1 = v1 ? deg[n1] : 0; if (d1 > CAP) d1 = CAP;
    int grp = lane >> 4, sub = lane & 15;
    const uint4* hp = (const uint4*)hprev;

    int idx0 = bucket[(size_t)n0 * CAP + lane];
    int idx1 = v1 ? bucket[(size_t)n1 * CAP + lane] : 0;

    uint4 s0v = hp[(size_t)n0 * 16 + sub];
    uint4 s1v = v1 ? hp[(size_t)n1 * 16 + sub] : make_uint4(0u, 0u, 0u, 0u);

    float a0[8] = {0.f,0.f,0.f,0.f,0.f,0.f,0.f,0.f};
    float a1[8] = {0.f,0.f,0.f,0.f,0.f,0.f,0.f,0.f};
    int dmax = d0 > d1 ? d0 : d1;

    auto issue = [&](int t, bool (&p0)[4], bool (&p1)[4],
                     uint4 (&w0)[4], uint4 (&w1)[4]) {
        #pragma unroll
        for (int q = 0; q < 4; ++q) {
            int e = t + q * 4 + grp;
            int s0 = __shfl(idx0, e & 63);
            int s1 = __shfl(idx1, e & 63);
            p0[q] = e < d0;
            p1[q] = e < d1;
            int r0 = p0[q] ? s0 : n0;
            int r1 = p1[q] ? s1 : n0;
            w0[q] = hp[(size_t)r0 * 16 + sub];
            w1[q] = hp[(size_t)r1 * 16 + sub];
        }
    };
    auto accum = [&](bool (&p0)[4], bool (&p1)[4],
                     uint4 (&w0)[4], uint4 (&w1)[4]) {
        #pragma unroll
        for (int q = 0; q < 4; ++q) {
            if (p0[q]) {
                uint4 v = w0[q];
                a0[0] += bf_lo(v.x); a0[1] += bf_hi(v.x);
                a0[2] += bf_lo(v.y); a0[3] += bf_hi(v.y);
                a0[4] += bf_lo(v.z); a0[5] += bf_hi(v.z);
                a0[6] += bf_lo(v.w); a0[7] += bf_hi(v.w);
            }
            if (p1[q]) {
                uint4 v = w1[q];
                a1[0] += bf_lo(v.x); a1[1] += bf_hi(v.x);
                a1[2] += bf_lo(v.y); a1[3] += bf_hi(v.y);
                a1[4] += bf_lo(v.z); a1[5] += bf_hi(v.z);
                a1[6] += bf_lo(v.w); a1[7] += bf_hi(v.w);
            }
        }
    };

    if (dmax > 0) {
        bool cp0[4], cp1[4];
        uint4 cw0[4], cw1[4];
        issue(0, cp0, cp1, cw0, cw1);
        for (int t = 16; t < dmax; t += 16) {
            bool np0[4], np1[4];
            uint4 nw0[4], nw1[4];
            issue(t, np0, np1, nw0, nw1);
            accum(cp0, cp1, cw0, cw1);
            #pragma unroll
            for (int q = 0; q < 4; ++q) {
                cp0[q] = np0[q]; cp1[q] = np1[q];
                cw0[q] = nw0[q]; cw1[q] = nw1[q];
            }
        }
        accum(cp0, cp1, cw0, cw1);
    }

    #pragma unroll
    for (int j = 0; j < 8; ++j) {
        a0[j] += __shfl_xor(a0[j], 16);
        a0[j] += __shfl_xor(a0[j], 32);
        a1[j] += __shfl_xor(a1[j], 16);
        a1[j] += __shfl_xor(a1[j], 32);
    }

    a0[0] += bf_lo(s0v.x); a0[1] += bf_hi(s0v.x);
    a0[2] += bf_lo(s0v.y); a0[3] += bf_hi(s0v.y);
    a0[4] += bf_lo(s0v.z); a0[5] += bf_hi(s0v.z);
    a0[6] += bf_lo(s0v.w); a0[7] += bf_hi(s0v.w);
    if (v1) {
        a1[0] += bf_lo(s1v.x); a1[1] += bf_hi(s1v.x);
        a1[2] += bf_lo(s1v.y); a1[3] += bf_hi(s1v.y);
        a1[4] += bf_lo(s1v.z); a1[5] += bf_hi(s1v.z);
        a1[6] += bf_lo(s1v.w); a1[7] += bf_hi(s1v.w);
    }

    if (grp == 0) {
        uint4 o;
        o.x = (unsigned)f2bf(a0[0]) | ((unsigned)f2bf(a0[1]) << 16);
        o.y = (unsigned)f2bf(a0[2]) | ((unsigned)f2bf(a0[3]) << 16);
        o.z = (unsigned)f2bf(a0[4]) | ((unsigned)f2bf(a0[5]) << 16);
        o.w = (unsigned)f2bf(a0[6]) | ((unsigned)f2bf(a0[7]) << 16);
        ((uint4*)y)[(size_t)n0 * 16 + sub] = o;
        if (v1) {
            uint4 p;
            p.x = (unsigned)f2bf(a1[0]) | ((unsigned)f2bf(a1[1]) << 16);
            p.y = (unsigned)f2bf(a1[2]) | ((unsigned)f2bf(a1[3]) << 16);
            p.z = (unsigned)f2bf(a1[4]) | ((unsigned)f2bf(a1[5]) << 16);
            p.w = (unsigned)f2bf(a1[6]) | ((unsigned)f2bf(a1[7]) << 16);
            ((uint4*)y)[(size_t)n1 * 16 + sub] = p;
        }
    }
}

// ---------------------------------------------------------------------------
// Fused layer GEMM (64-row tile, 3 barriers): h = relu((relu((A@W1)*a1+b1_)
// @W2)+b2_) + wave-level pooled reduction (no LDS stash). Wt2 prefetched
// into registers before GEMM1. outh==NULL on the last layer (dead write).
// Pooling: each wave reduces its 16 rows per column via shfl_xor(16/32);
// batch is sorted so the wave's rows span contiguous graphs [gmn,gmx].
// ---------------------------------------------------------------------------
__global__ __launch_bounds__(256) void layer_fused(const unsigned short* __restrict__ A,
                                                   const unsigned short* __restrict__ Wt1,
                                                   const unsigned short* __restrict__ Wt2,
                                                   const float* __restrict__ ea1,
                                                   const float* __restrict__ eb1,
                                                   const float* __restrict__ ea2,
                                                   const float* __restrict__ eb2,
                                                   const int* __restrict__ batch,
                                                   float* __restrict__ pooled, int loff,
                                                   unsigned short* __restrict__ outh, int n) {
    __shared__ unsigned short As[64][136];
    __shared__ unsigned short Ws[128][136];
    int tid = threadIdx.x;
    int row0 = blockIdx.x * 64;
    int wave = tid >> 6, lane = tid & 63;
    int m0 = wave * 16;
    int lrow = lane & 15, lq = lane >> 4;

    #pragma unroll
    for (int i = 0; i < 4; ++i) {
        int idx = tid + i * 256;
        int r = idx >> 4, c = (idx & 15) * 8;
        ushort8 v = (ushort8)0;
        if (row0 + r < n) v = *(const ushort8*)&A[(size_t)(row0 + r) * D_FEAT + c];
        *(ushort8*)&As[r][c] = v;
    }
    #pragma unroll
    for (int i = 0; i < 8; ++i) {
        int idx = tid + i * 256;
        int r = idx >> 4, c = (idx & 15) * 8;
        *(ushort8*)&Ws[r][c] = *(const ushort8*)&Wt1[(size_t)r * D_FEAT + c];
    }

    ushort8 w2reg[8];
    #pragma unroll
    for (int i = 0; i < 8; ++i) {
        int idx = tid + i * 256;
        int r = idx >> 4, c = (idx & 15) * 8;
        w2reg[i] = *(const ushort8*)&Wt2[(size_t)r * D_FEAT + c];
    }

    // per-lane graph ids for its 4 rows (gr0 is 4-aligned)
    int gr0 = row0 + m0 + lq * 4;
    int bq[4];
    if (gr0 + 3 < n) {
        int4 b4 = *(const int4*)&batch[gr0];
        bq[0] = b4.x; bq[1] = b4.y; bq[2] = b4.z; bq[3] = b4.w;
    } else {
        #pragma unroll
        for (int r = 0; r < 4; ++r)
            bq[r] = (gr0 + r < n) ? batch[gr0 + r] : -1;
    }
    __syncthreads();

    // ---- GEMM 1 ----
    f32x4 acc[8] = {};
    #pragma unroll
    for (int t = 0; t < 4; ++t) {
        bf16x8 a = *(const bf16x8*)&As[m0 + lrow][t * 32 + lq * 8];
        #pragma unroll
        for (int nt = 0; nt < 8; ++nt) {
            bf16x8 b = *(const bf16x8*)&Ws[nt * 16 + lrow][t * 32 + lq * 8];
            acc[nt] = __builtin_amdgcn_mfma_f32_16x16x32_bf16(a, b, acc[nt], 0, 0, 0);
        }
    }
    __syncthreads();

    // epilogue 1 -> z (bf16) into As; store prefetched Wt2 into Ws
    #pragma unroll
    for (int nt = 0; nt < 8; ++nt) {
        int col = nt * 16 + lrow;
        float al = ea1[col], be = eb1[col];
        #pragma unroll
        for (int r = 0; r < 4; ++r) {
            float v = fmaxf(fmaf(acc[nt][r], al, be), 0.f);
            As[m0 + lq * 4 + r][col] = f2bf(v);
        }
    }
    #pragma unroll
    for (int i = 0; i < 8; ++i) {
        int idx = tid + i * 256;
        int r = idx >> 4, c = (idx & 15) * 8;
        *(ushort8*)&Ws[r][c] = w2reg[i];
    }
    __syncthreads();

    // ---- GEMM 2 ----
    f32x4 acc2[8] = {};
    #pragma unroll
    for (int t = 0; t < 4; ++t) {
        bf16x8 a = *(const bf16x8*)&As[m0 + lrow][t * 32 + lq * 8];
        #pragma unroll
        for (int nt = 0; nt < 8; ++nt) {
            bf16x8 b = *(const bf16x8*)&Ws[nt * 16 + lrow][t * 32 + lq * 8];
            acc2[nt] = __builtin_amdgcn_mfma_f32_16x16x32_bf16(a, b, acc2[nt], 0, 0, 0);
        }
    }

    // epilogue 2: compute bf16-rounded h once; global write + wave pooling
    float vv[8][4];
    #pragma unroll
    for (int nt = 0; nt < 8; ++nt) {
        int col = nt * 16 + lrow;
        float al = ea2[col], be = eb2[col];
        #pragma unroll
        for (int r = 0; r < 4; ++r) {
            unsigned short hb = f2bf(fmaxf(fmaf(acc2[nt][r], al, be), 0.f));
            vv[nt][r] = bf2f(hb);
            if (outh) {
                int grow = row0 + m0 + lq * 4 + r;
                if (grow < n) outh[(size_t)grow * D_FEAT + col] = hb;
            }
        }
    }

    // wave-level pooling: rows of a wave span contiguous graphs [gmn,gmx]
    int gmn = 0x7fffffff, gmx = -1;
    #pragma unroll
    for (int r = 0; r < 4; ++r) {
        if (bq[r] >= 0) {
            gmn = bq[r] < gmn ? bq[r] : gmn;
            gmx = bq[r] > gmx ? bq[r] : gmx;
        }
    }
    {
        int t;
        t = __shfl_xor(gmn, 16); gmn = t < gmn ? t : gmn;
        t = __shfl_xor(gmn, 32); gmn = t < gmn ? t : gmn;
        t = __shfl_xor(gmx, 16); gmx = t > gmx ? t : gmx;
        t = __shfl_xor(gmx, 32); gmx = t > gmx ? t : gmx;
    }
    for (int seg = gmn; seg <= gmx; ++seg) {
        #pragma unroll
        for (int nt = 0; nt < 8; ++nt) {
            float s = 0.f;
            #pragma unroll
            for (int r = 0; r < 4; ++r)
                if (bq[r] == seg) s += vv[nt][r];
            s += __shfl_xor(s, 16);
            s += __shfl_xor(s, 32);
            if (lq == 0 && s != 0.f)
                atomicAdd(&pooled[(size_t)seg * POOL_DIM + loff + nt * 16 + lrow], s);
        }
    }
}

// ---------------------------------------------------------------------------
// Fused MLP head: 128 blocks x 384 threads, 4 graphs/block. fc1 (coalesced
// W1, graphs in registers, k ascending) -> f1 in LDS -> fc2 by threads 0..39.
// ---------------------------------------------------------------------------
__global__ __launch_bounds__(384) void head_kernel(const float* __restrict__ pooled,
                                                   const float* __restrict__ W1,
                                                   const float* __restrict__ b1v,
                                                   const float* __restrict__ W2,
                                                   const float* __restrict__ b2v,
                                                   float* __restrict__ out) {
    __shared__ float f1[4][POOL_DIM];
    int j = threadIdx.x;                   // 0..383
    int g0 = blockIdx.x * 4;
    const float* pr = pooled + (size_t)g0 * POOL_DIM;
    float bb = b1v[j];
    float s0 = bb, s1 = bb, s2 = bb, s3 = bb;
    for (int k0 = 0; k0 < POOL_DIM; k0 += 8) {
        float w[8];
        #pragma unroll
        for (int i = 0; i < 8; ++i)
            w[i] = W1[(size_t)(k0 + i) * POOL_DIM + j];
        #pragma unroll
        for (int i = 0; i < 8; ++i) {
            int k = k0 + i;
            s0 = fmaf(pr[k],                w[i], s0);
            s1 = fmaf(pr[POOL_DIM + k],     w[i], s1);
            s2 = fmaf(pr[2 * POOL_DIM + k], w[i], s2);
            s3 = fmaf(pr[3 * POOL_DIM + k], w[i], s3);
        }
    }
    f1[0][j] = fmaxf(s0, 0.f);
    f1[1][j] = fmaxf(s1, 0.f);
    f1[2][j] = fmaxf(s2, 0.f);
    f1[3][j] = fmaxf(s3, 0.f);
    __syncthreads();
    if (j < 4 * N_CLASSES) {
        int g = j / N_CLASSES, c = j % N_CLASSES;
        float s = b2v[c];
        for (int k = 0; k < POOL_DIM; ++k)
            s = fmaf(f1[g][k], W2[(size_t)k * N_CLASSES + c], s);
        out[(size_t)(g0 + g) * N_CLASSES + c] = s;
    }
}

// ---------------------------------------------------------------------------
extern "C" void kernel_launch(void* const* d_in, const int* in_sizes, int n_in,
                              void* d_out, int out_size, void* d_ws, size_t ws_size,
                              hipStream_t stream) {
    const float* x      = (const float*)d_in[0];
    const int*   ei     = (const int*)  d_in[1];
    const int*   batch  = (const int*)  d_in[2];
    const float* W1     = (const float*)d_in[3];
    const float* b1     = (const float*)d_in[4];
    const float* gamma  = (const float*)d_in[5];
    const float* beta   = (const float*)d_in[6];
    const float* rm     = (const float*)d_in[7];
    const float* rv     = (const float*)d_in[8];
    const float* W2     = (const float*)d_in[9];
    const float* b2     = (const float*)d_in[10];
    const float* lin1W  = (const float*)d_in[11];
    const float* lin1b  = (const float*)d_in[12];
    const float* lin2W  = (const float*)d_in[13];
    const float* lin2b  = (const float*)d_in[14];
    float* out = (float*)d_out;

    const int N = in_sizes[0] / D_FEAT;   // 50000
    const int E = in_sizes[1] / 2;        // 800000

    char* ws = (char*)d_ws;
    auto carve = [&](size_t bytes) {
        char* p = ws;
        ws += (bytes + 255) & ~(size_t)255;
        return p;
    };
    int*   cursor    = (int*)  carve((size_t)N * 4);
    int*   cnts      = (int*)  carve((size_t)NBINS * 256 * 4);
    int*   bucket    = (int*)  carve((size_t)N * CAP * 4);
    int2*  pairs     = (int2*) carve((size_t)NBINS * 256 * SLABCAP * 8);
    float* ea        = (float*)carve((size_t)2 * N_LAYERS * D_FEAT * 4);
    float* eb        = (float*)carve((size_t)2 * N_LAYERS * D_FEAT * 4);
    unsigned short* Wt   = (unsigned short*)carve((size_t)2 * N_LAYERS * D_FEAT * D_FEAT * 2);
    unsigned short* xb   = (unsigned short*)carve((size_t)N * D_FEAT * 2);
    unsigned short* ybuf = (unsigned short*)carve((size_t)N * D_FEAT * 2);
    unsigned short* hbuf = (unsigned short*)carve((size_t)N * D_FEAT * 2);
    float* pooled    = (float*)carve((size_t)N_GRAPHS * POOL_DIM * 4);

    // merged setup grid layout
    const int n4 = N * D_FEAT / 4;
    const int B0 = (n4 + 255) / 256;                            // cvt_x
    const int B1 = B0 + 24;                                     // cvt_w: 6 slots x 4 tiles
    const int B2 = B1 + 2;                                      // prep
    const int B3 = B2 + (N + 255) / 256;                        // cursor zero
    const int B4 = B3 + (N_GRAPHS * POOL_DIM + 255) / 256;      // pooled zero
    const int B5 = B4 + 256;                                    // bin

    setup_kernel<<<B5, 256, 0, stream>>>(x, xb, W1, W2, Wt, b1, gamma, beta,
                                         rm, rv, b2, ea, eb, cursor, pooled,
                                         ei, pairs, cnts, E,
                                         N, n4, B0, B1, B2, B3, B4);
    fill_v3<<<8 * 64, 256, 0, stream>>>(pairs, cnts, cursor, bucket);

    const unsigned short* hprev = xb;
    for (int l = 0; l < N_LAYERS; ++l) {
        agg_kernel<<<(N + 7) / 8, 256, 0, stream>>>(hprev, cursor, bucket, ybuf, N);
        unsigned short* outh = (l == N_LAYERS - 1) ? nullptr : hbuf;
        layer_fused<<<(N + 63) / 64, 256, 0, stream>>>(ybuf,
                      Wt + (size_t)(2 * l) * D_FEAT * D_FEAT,
                      Wt + (size_t)(2 * l + 1) * D_FEAT * D_FEAT,
                      ea + (size_t)(2 * l) * D_FEAT,
                      eb + (size_t)(2 * l) * D_FEAT,
                      ea + (size_t)(2 * l + 1) * D_FEAT,
                      eb + (size_t)(2 * l + 1) * D_FEAT,
                      batch, pooled, l * D_FEAT, outh, N);
        hprev = hbuf;
    }
    head_kernel<<<N_GRAPHS / 4, 384, 0, stream>>>(pooled, lin1W, lin1b, lin2W, lin2b, out);
}